// Round 1
// baseline (475.708 us; speedup 1.0000x reference)
//
#include <hip/hip_runtime.h>
#include <hip/hip_bf16.h>

// Problem: B=16, C=512, H=W=64 -> N=4096, CP=64.
// x:(B,C,N) wq/wk/wv:(64,512) b*: (64,) wo:(512,64) bo:(512,) gamma:(1,)
// out = gamma * (wo @ softmax((wk x)(wq x)^T) @ (wv x) + bo) + x

#define NN 4096
#define CIN 512
#define CPD 64

// ---------------- K1: QKV projections (fp32 GEMM, 192x512 @ 512x4096 per b)
__global__ __launch_bounds__(256) void k_qkv(
    const float* __restrict__ x,
    const float* __restrict__ wq, const float* __restrict__ bq,
    const float* __restrict__ wk, const float* __restrict__ bk,
    const float* __restrict__ wv, const float* __restrict__ bv,
    float* __restrict__ q, float* __restrict__ k, float* __restrict__ v)
{
    const int n0 = blockIdx.x * 128;
    const int p  = blockIdx.y;   // 0=q,1=k,2=v
    const int b  = blockIdx.z;
    const float* w   = (p == 0) ? wq : (p == 1) ? wk : wv;
    const float* bia = (p == 0) ? bq : (p == 1) ? bk : bv;
    float* out = (p == 0) ? q : (p == 1) ? k : v;

    __shared__ float xs[32][128];   // 16 KB
    __shared__ float wsh[64][32];   // 8 KB

    const int tid = threadIdx.x;
    const int tx  = tid & 31;   // n-group: 4 consecutive n via float4
    const int ty  = tid >> 5;   // o-group: 8 groups of 8 outputs

    float acc[8][4];
    #pragma unroll
    for (int i = 0; i < 8; ++i)
        #pragma unroll
        for (int d = 0; d < 4; ++d) acc[i][d] = 0.f;

    const float* xb = x + ((size_t)b * CIN) * NN + n0;

    for (int c0 = 0; c0 < CIN; c0 += 32) {
        // stage x chunk: 32c x 128n (1024 float4, 4 per thread)
        #pragma unroll
        for (int it = 0; it < 4; ++it) {
            int e = tid + it * 256;
            int row = e >> 5;
            int col = (e & 31) * 4;
            float4 val = *(const float4*)(xb + (size_t)(c0 + row) * NN + col);
            *(float4*)&xs[row][col] = val;
        }
        // stage w chunk: 64o x 32c (512 float4, 2 per thread)
        #pragma unroll
        for (int it = 0; it < 2; ++it) {
            int e = tid + it * 256;
            int o  = e >> 3;
            int cg = (e & 7) * 4;
            float4 val = *(const float4*)(w + (size_t)o * CIN + c0 + cg);
            *(float4*)&wsh[o][cg] = val;
        }
        __syncthreads();
        #pragma unroll
        for (int cc = 0; cc < 32; ++cc) {
            float4 xv = *(const float4*)&xs[cc][tx * 4];
            #pragma unroll
            for (int i = 0; i < 8; ++i) {
                float wv_ = wsh[ty * 8 + i][cc];   // 2 addrs/wave -> free
                acc[i][0] += wv_ * xv.x;
                acc[i][1] += wv_ * xv.y;
                acc[i][2] += wv_ * xv.z;
                acc[i][3] += wv_ * xv.w;
            }
        }
        __syncthreads();
    }

    float* ob = out + ((size_t)b * CPD) * NN + n0;
    #pragma unroll
    for (int i = 0; i < 8; ++i) {
        int o = ty * 8 + i;
        float bs = bia[o];
        float4 r;
        r.x = acc[i][0] + bs; r.y = acc[i][1] + bs;
        r.z = acc[i][2] + bs; r.w = acc[i][3] + bs;
        *(float4*)(ob + (size_t)o * NN + tx * 4) = r;
    }
}

// ---------------- K2: energy partials: epart[b][split][i][j] = sum_{n chunk} k[i,n]q[j,n]
__global__ __launch_bounds__(256) void k_energy(
    const float* __restrict__ qp, const float* __restrict__ kp,
    float* __restrict__ epart)   // [16][64][64][64]
{
    const int split = blockIdx.x;   // 64 chunks of 64 n
    const int b     = blockIdx.y;
    const int n0    = split * 64;
    __shared__ float ks[64][65];
    __shared__ float qs[64][65];
    const int tid = threadIdx.x;

    const float* kb = kp + ((size_t)b * CPD) * NN + n0;
    const float* qb = qp + ((size_t)b * CPD) * NN + n0;
    #pragma unroll
    for (int it = 0; it < 16; ++it) {
        int e = tid + it * 256;
        int row = e >> 6, col = e & 63;
        ks[row][col] = kb[(size_t)row * NN + col];
        qs[row][col] = qb[(size_t)row * NN + col];
    }
    __syncthreads();

    const int ti = (tid >> 4) * 4;
    const int tj = (tid & 15) * 4;
    float acc[4][4];
    #pragma unroll
    for (int a = 0; a < 4; ++a)
        #pragma unroll
        for (int d = 0; d < 4; ++d) acc[a][d] = 0.f;

    for (int n = 0; n < 64; ++n) {
        float kv[4], qv[4];
        #pragma unroll
        for (int a = 0; a < 4; ++a) kv[a] = ks[ti + a][n];
        #pragma unroll
        for (int a = 0; a < 4; ++a) qv[a] = qs[tj + a][n];
        #pragma unroll
        for (int a = 0; a < 4; ++a)
            #pragma unroll
            for (int d = 0; d < 4; ++d) acc[a][d] += kv[a] * qv[d];
    }
    float* ep = epart + ((size_t)b * 64 + split) * 4096;
    #pragma unroll
    for (int a = 0; a < 4; ++a)
        #pragma unroll
        for (int d = 0; d < 4; ++d)
            ep[(ti + a) * 64 + tj + d] = acc[a][d];
}

// ---------------- K3: sum partials + softmax over j (one wave per (b,i) row)
__global__ __launch_bounds__(64) void k_softmax(
    const float* __restrict__ epart, float* __restrict__ attn)
{
    const int i = blockIdx.x;
    const int b = blockIdx.y;
    const int j = threadIdx.x;
    const float* ep = epart + (size_t)b * 64 * 4096 + i * 64 + j;
    float s = 0.f;
    #pragma unroll
    for (int sp = 0; sp < 64; ++sp) s += ep[(size_t)sp * 4096];
    float m = s;
    #pragma unroll
    for (int off = 32; off; off >>= 1) m = fmaxf(m, __shfl_xor(m, off));
    float e = __expf(s - m);
    float sum = e;
    #pragma unroll
    for (int off = 32; off; off >>= 1) sum += __shfl_xor(sum, off);
    attn[((size_t)b * 64 + i) * 64 + j] = e / sum;
}

// ---------------- K4: av[b][i][n] = sum_j attn[i][j] * v[j][n]
__global__ __launch_bounds__(256) void k_attnv(
    const float* __restrict__ attn, const float* __restrict__ vp,
    float* __restrict__ av)
{
    const int b = blockIdx.y;
    const int n = blockIdx.x * 256 + threadIdx.x;
    __shared__ float as_[64][65];
    const int tid = threadIdx.x;
    const float* ab = attn + (size_t)b * 4096;
    #pragma unroll
    for (int it = 0; it < 16; ++it) {
        int e = tid + it * 256;
        as_[e >> 6][e & 63] = ab[e];
    }
    __syncthreads();
    const float* vb = vp + ((size_t)b * CPD) * NN + n;
    float vr[64];
    #pragma unroll
    for (int j = 0; j < 64; ++j) vr[j] = vb[(size_t)j * NN];
    float* ob = av + ((size_t)b * CPD) * NN + n;
    for (int i = 0; i < 64; ++i) {
        float acc = 0.f;
        #pragma unroll
        for (int j = 0; j < 64; ++j) acc += as_[i][j] * vr[j];   // LDS broadcast
        ob[(size_t)i * NN] = acc;
    }
}

// ---------------- K5: out = gamma * (wo @ av + bo) + x
__global__ __launch_bounds__(256) void k_out(
    const float* __restrict__ av, const float* __restrict__ wo,
    const float* __restrict__ bo, const float* __restrict__ gamma,
    const float* __restrict__ x, float* __restrict__ out)
{
    const int n0 = blockIdx.x * 128;
    const int c0 = blockIdx.y * 64;
    const int b  = blockIdx.z;
    __shared__ float avs[64][128];  // 32 KB
    __shared__ float wos[64][64];   // 16 KB
    const int tid = threadIdx.x;
    const int tx  = tid & 31;
    const int ty  = tid >> 5;

    const float* avb = av + ((size_t)b * CPD) * NN + n0;
    #pragma unroll
    for (int it = 0; it < 8; ++it) {
        int e = tid + it * 256;
        int row = e >> 5, col = (e & 31) * 4;
        *(float4*)&avs[row][col] = *(const float4*)(avb + (size_t)row * NN + col);
    }
    #pragma unroll
    for (int it = 0; it < 4; ++it) {
        int e = tid + it * 256;
        int row = e >> 4, col = (e & 15) * 4;
        *(float4*)&wos[row][col] = *(const float4*)(wo + (size_t)(c0 + row) * CPD + col);
    }
    __syncthreads();

    float acc[8][4];
    #pragma unroll
    for (int i = 0; i < 8; ++i)
        #pragma unroll
        for (int d = 0; d < 4; ++d) acc[i][d] = 0.f;

    #pragma unroll 8
    for (int o = 0; o < 64; ++o) {
        float4 xv = *(const float4*)&avs[o][tx * 4];
        #pragma unroll
        for (int i = 0; i < 8; ++i) {
            float wv_ = wos[ty * 8 + i][o];   // 2 addrs/wave -> free
            acc[i][0] += wv_ * xv.x;
            acc[i][1] += wv_ * xv.y;
            acc[i][2] += wv_ * xv.z;
            acc[i][3] += wv_ * xv.w;
        }
    }

    const float g = gamma[0];
    const float* xb = x + ((size_t)b * CIN + c0) * NN + n0;
    float* ob = out + ((size_t)b * CIN + c0) * NN + n0;
    #pragma unroll
    for (int i = 0; i < 8; ++i) {
        int cl = ty * 8 + i;
        float bs = bo[c0 + cl];
        float4 xr = *(const float4*)(xb + (size_t)cl * NN + tx * 4);
        float4 r;
        r.x = g * (acc[i][0] + bs) + xr.x;
        r.y = g * (acc[i][1] + bs) + xr.y;
        r.z = g * (acc[i][2] + bs) + xr.z;
        r.w = g * (acc[i][3] + bs) + xr.w;
        *(float4*)(ob + (size_t)cl * NN + tx * 4) = r;
    }
}

extern "C" void kernel_launch(void* const* d_in, const int* in_sizes, int n_in,
                              void* d_out, int out_size, void* d_ws, size_t ws_size,
                              hipStream_t stream) {
    const float* x  = (const float*)d_in[0];
    const float* wq = (const float*)d_in[1];
    const float* bq = (const float*)d_in[2];
    const float* wk = (const float*)d_in[3];
    const float* bk = (const float*)d_in[4];
    const float* wv = (const float*)d_in[5];
    const float* bv = (const float*)d_in[6];
    const float* wo = (const float*)d_in[7];
    const float* bo = (const float*)d_in[8];
    const float* gm = (const float*)d_in[9];
    float* out = (float*)d_out;

    // workspace layout (floats); av aliases q (q dead after k_energy)
    float* ws    = (float*)d_ws;
    float* q     = ws;                       // 16*64*4096
    float* k     = ws + 4194304;
    float* v     = ws + 8388608;
    float* epart = ws + 12582912;            // 16*64*64*64
    float* attn  = ws + 16777216;            // 16*64*64
    float* av    = q;                        // alias: q dead after k_energy

    dim3 g1(32, 3, 16);
    k_qkv<<<g1, 256, 0, stream>>>(x, wq, bq, wk, bk, wv, bv, q, k, v);
    dim3 g2(64, 16);
    k_energy<<<g2, 256, 0, stream>>>(q, k, epart);
    dim3 g3(64, 16);
    k_softmax<<<g3, 64, 0, stream>>>(epart, attn);
    dim3 g4(16, 16);
    k_attnv<<<g4, 256, 0, stream>>>(attn, v, av);
    dim3 g5(32, 8, 16);
    k_out<<<g5, 256, 0, stream>>>(av, wo, bo, gm, x, out);
}

// Round 2
// 368.933 us; speedup vs baseline: 1.2894x; 1.2894x over previous
//
#include <hip/hip_runtime.h>
#include <hip/hip_bf16.h>

// B=16, C=512, N=4096 (64x64), CP=64.  out = gamma*(wo@softmax((wk x)(wq x)^T)@(wv x)+bo)+x
// bf16 MFMA pipeline. Layouts: xt[b][n][c], q/k[cp][n], vt[n][cp], attn[i][j], avt[n][i].

#define NN 4096
#define CIN 512
#define CPD 64

typedef short s8v __attribute__((ext_vector_type(8)));
typedef float f4v __attribute__((ext_vector_type(4)));

__device__ __forceinline__ unsigned short f2bf(float f) {
    union { float f; unsigned int u; } c; c.f = f;
    unsigned int r = c.u + 0x7FFFu + ((c.u >> 16) & 1u);   // RNE
    return (unsigned short)(r >> 16);
}

// ---------------- K0: transpose + convert  x[b][c][n] fp32 -> xt[bl][n][c] bf16 (b-chunk of 8)
__global__ __launch_bounds__(256) void k_prep(
    const float* __restrict__ x, unsigned short* __restrict__ xt, int b_base)
{
    const int nt = blockIdx.x;   // 64 tiles of 64 n
    const int ct = blockIdx.y;   // 8 tiles of 64 c
    const int bl = blockIdx.z;   // local b
    const int b  = b_base + bl;
    __shared__ unsigned short lds[64][68];   // [c][n], pad for banks
    const int t = threadIdx.x;

    const float* xb = x + ((size_t)b * CIN + ct * 64) * NN + nt * 64;
    #pragma unroll
    for (int i = 0; i < 4; ++i) {
        int c = i * 16 + (t >> 4);
        int n = (t & 15) * 4;
        float4 v = *(const float4*)(xb + (size_t)c * NN + n);
        lds[c][n]     = f2bf(v.x);
        lds[c][n + 1] = f2bf(v.y);
        lds[c][n + 2] = f2bf(v.z);
        lds[c][n + 3] = f2bf(v.w);
    }
    __syncthreads();
    unsigned short* xtb = xt + ((size_t)bl * NN + nt * 64) * CIN + ct * 64;
    #pragma unroll
    for (int pass = 0; pass < 2; ++pass) {
        int n  = (t >> 3) + pass * 32;
        int c8 = (t & 7) * 8;
        unsigned short tmp[8];
        #pragma unroll
        for (int j = 0; j < 8; ++j) tmp[j] = lds[c8 + j][n];
        *(uint4*)(xtb + (size_t)n * CIN + c8) = *(const uint4*)tmp;
    }
}

// ---------------- K1: QKV via MFMA. A=w (LDS, swizzled), B=xt direct global.
__global__ __launch_bounds__(256) void k_qkv(
    const unsigned short* __restrict__ xt,
    const float* __restrict__ wq, const float* __restrict__ bq,
    const float* __restrict__ wk, const float* __restrict__ bk,
    const float* __restrict__ wv, const float* __restrict__ bv,
    unsigned short* __restrict__ q, unsigned short* __restrict__ k,
    unsigned short* __restrict__ vt, int b_base)
{
    const int nb = blockIdx.x;   // 16 tiles of 256 n
    const int p  = blockIdx.y;   // 0=q,1=k,2=v
    const int bl = blockIdx.z;
    const int b  = b_base + bl;
    const float* w    = (p == 0) ? wq : (p == 1) ? wk : wv;
    const float* bias = (p == 0) ? bq : (p == 1) ? bk : bv;

    __shared__ unsigned short wl[64 * 512];   // 64 KB, XOR-swizzled rows
    const int t = threadIdx.x;

    // stage full w (fp32 -> bf16), swizzle c ^= (o&7)*8 so A-frag reads are 2-way (free)
    #pragma unroll
    for (int i = 0; i < 16; ++i) {
        int lin = i * 256 + t;
        int o   = lin >> 6;
        int c8  = (lin & 63) * 8;
        float4 v0 = *(const float4*)(w + (size_t)o * CIN + c8);
        float4 v1 = *(const float4*)(w + (size_t)o * CIN + c8 + 4);
        unsigned short tmp[8] = { f2bf(v0.x), f2bf(v0.y), f2bf(v0.z), f2bf(v0.w),
                                  f2bf(v1.x), f2bf(v1.y), f2bf(v1.z), f2bf(v1.w) };
        int sw = c8 ^ ((o & 7) * 8);
        *(uint4*)(wl + o * 512 + sw) = *(const uint4*)tmp;
    }
    __syncthreads();

    const int wv_  = t >> 6;
    const int L    = t & 63;
    const int quad = L >> 4;
    const int l15  = L & 15;
    const int n0   = nb * 256 + wv_ * 64;
    const unsigned short* xb = xt + (size_t)bl * NN * CIN;   // [n][c]

    f4v acc[4][4];
    #pragma unroll
    for (int a = 0; a < 4; ++a)
        #pragma unroll
        for (int d = 0; d < 4; ++d) acc[a][d] = (f4v){0.f, 0.f, 0.f, 0.f};

    #pragma unroll
    for (int ks = 0; ks < 16; ++ks) {
        const int c = ks * 32 + quad * 8;
        s8v bfr[4];
        #pragma unroll
        for (int nt2 = 0; nt2 < 4; ++nt2)
            bfr[nt2] = *(const s8v*)(xb + (size_t)(n0 + nt2 * 16 + l15) * CIN + c);
        s8v afr[4];
        #pragma unroll
        for (int ot = 0; ot < 4; ++ot) {
            int o = ot * 16 + l15;
            afr[ot] = *(const s8v*)(wl + o * 512 + (c ^ ((o & 7) * 8)));
        }
        #pragma unroll
        for (int ot = 0; ot < 4; ++ot)
            #pragma unroll
            for (int nt2 = 0; nt2 < 4; ++nt2)
                acc[ot][nt2] = __builtin_amdgcn_mfma_f32_16x16x32_bf16(
                    afr[ot], bfr[nt2], acc[ot][nt2], 0, 0, 0);
    }

    if (p < 2) {
        unsigned short* outp = ((p == 0) ? q : k) + (size_t)b * CPD * NN;
        #pragma unroll
        for (int ot = 0; ot < 4; ++ot)
            #pragma unroll
            for (int r = 0; r < 4; ++r) {
                int o = ot * 16 + quad * 4 + r;
                float bs = bias[o];
                #pragma unroll
                for (int nt2 = 0; nt2 < 4; ++nt2) {
                    int n = n0 + nt2 * 16 + l15;
                    outp[(size_t)o * NN + n] = f2bf(acc[ot][nt2][r] + bs);
                }
            }
    } else {
        unsigned short* outp = vt + (size_t)b * NN * CPD;   // [n][cp]
        #pragma unroll
        for (int nt2 = 0; nt2 < 4; ++nt2) {
            int n = n0 + nt2 * 16 + l15;
            #pragma unroll
            for (int ot = 0; ot < 4; ++ot) {
                unsigned short tmp[4];
                #pragma unroll
                for (int r = 0; r < 4; ++r) {
                    int o = ot * 16 + quad * 4 + r;
                    tmp[r] = f2bf(acc[ot][nt2][r] + bias[o]);
                }
                *(uint2*)(outp + (size_t)n * CPD + ot * 16 + quad * 4) = *(const uint2*)tmp;
            }
        }
    }
}

// ---------------- K2: energy partials via MFMA (K-split 64, one wave per (split,b))
__global__ __launch_bounds__(64) void k_energy(
    const unsigned short* __restrict__ q, const unsigned short* __restrict__ k,
    float* __restrict__ epart)   // [b][64][64][64] fp32
{
    const int s = blockIdx.x;   // 64 K-chunks of 64 n
    const int b = blockIdx.y;
    const int L = threadIdx.x;
    const int quad = L >> 4, l15 = L & 15;
    const unsigned short* kb = k + (size_t)b * CPD * NN;
    const unsigned short* qb = q + (size_t)b * CPD * NN;

    f4v acc[4][4];
    #pragma unroll
    for (int a = 0; a < 4; ++a)
        #pragma unroll
        for (int d = 0; d < 4; ++d) acc[a][d] = (f4v){0.f, 0.f, 0.f, 0.f};

    #pragma unroll
    for (int ks = 0; ks < 2; ++ks) {
        const int n = s * 64 + ks * 32 + quad * 8;
        s8v af[4], bf_[4];
        #pragma unroll
        for (int it = 0; it < 4; ++it)
            af[it] = *(const s8v*)(kb + (size_t)(it * 16 + l15) * NN + n);
        #pragma unroll
        for (int jt = 0; jt < 4; ++jt)
            bf_[jt] = *(const s8v*)(qb + (size_t)(jt * 16 + l15) * NN + n);
        #pragma unroll
        for (int it = 0; it < 4; ++it)
            #pragma unroll
            for (int jt = 0; jt < 4; ++jt)
                acc[it][jt] = __builtin_amdgcn_mfma_f32_16x16x32_bf16(
                    af[it], bf_[jt], acc[it][jt], 0, 0, 0);
    }
    float* ep = epart + ((size_t)b * 64 + s) * 4096;
    #pragma unroll
    for (int it = 0; it < 4; ++it)
        #pragma unroll
        for (int jt = 0; jt < 4; ++jt)
            #pragma unroll
            for (int r = 0; r < 4; ++r)
                ep[(it * 16 + quad * 4 + r) * 64 + jt * 16 + l15] = acc[it][jt][r];
}

// ---------------- K3: sum K-splits + softmax over j -> attn bf16 [b][i][j]
__global__ __launch_bounds__(64) void k_softmax(
    const float* __restrict__ epart, unsigned short* __restrict__ attn)
{
    const int i = blockIdx.x;
    const int b = blockIdx.y;
    const int j = threadIdx.x;
    const float* ep = epart + (size_t)b * 64 * 4096 + i * 64 + j;
    float s = 0.f;
    #pragma unroll
    for (int sp = 0; sp < 64; ++sp) s += ep[(size_t)sp * 4096];
    float m = s;
    #pragma unroll
    for (int off = 32; off; off >>= 1) m = fmaxf(m, __shfl_xor(m, off));
    float e = __expf(s - m);
    float tot = e;
    #pragma unroll
    for (int off = 32; off; off >>= 1) tot += __shfl_xor(tot, off);
    attn[(size_t)b * 4096 + i * 64 + j] = f2bf(e / tot);
}

// ---------------- K4: avt[n][i] = sum_j vt[n][j] attn[i][j]  (MFMA, both operands direct)
__global__ __launch_bounds__(256) void k_attnv(
    const unsigned short* __restrict__ vt, const unsigned short* __restrict__ attn,
    unsigned short* __restrict__ avt)
{
    const int nb = blockIdx.x;   // 16 tiles of 256 n
    const int b  = blockIdx.y;
    const int t  = threadIdx.x;
    const int wv_ = t >> 6, L = t & 63, quad = L >> 4, l15 = L & 15;
    const int n0 = nb * 256 + wv_ * 64;
    const unsigned short* vtb = vt + (size_t)b * NN * CPD;
    const unsigned short* ab  = attn + (size_t)b * 4096;

    f4v acc[4][4];   // [mt(n)][it(i)]
    #pragma unroll
    for (int a = 0; a < 4; ++a)
        #pragma unroll
        for (int d = 0; d < 4; ++d) acc[a][d] = (f4v){0.f, 0.f, 0.f, 0.f};

    #pragma unroll
    for (int ks = 0; ks < 2; ++ks) {
        const int jc = ks * 32 + quad * 8;
        s8v af[4], bf_[4];
        #pragma unroll
        for (int mt = 0; mt < 4; ++mt)
            af[mt] = *(const s8v*)(vtb + (size_t)(n0 + mt * 16 + l15) * CPD + jc);
        #pragma unroll
        for (int it = 0; it < 4; ++it)
            bf_[it] = *(const s8v*)(ab + (size_t)(it * 16 + l15) * 64 + jc);
        #pragma unroll
        for (int mt = 0; mt < 4; ++mt)
            #pragma unroll
            for (int it = 0; it < 4; ++it)
                acc[mt][it] = __builtin_amdgcn_mfma_f32_16x16x32_bf16(
                    af[mt], bf_[it], acc[mt][it], 0, 0, 0);
    }
    unsigned short* ob = avt + (size_t)b * NN * CPD;
    #pragma unroll
    for (int mt = 0; mt < 4; ++mt)
        #pragma unroll
        for (int it = 0; it < 4; ++it) {
            int i = it * 16 + l15;
            #pragma unroll
            for (int r = 0; r < 4; ++r) {
                int n = n0 + mt * 16 + quad * 4 + r;
                ob[(size_t)n * CPD + i] = f2bf(acc[mt][it][r]);
            }
        }
}

// ---------------- K5: out = gamma*(wo@av + bo) + x   (A=wo LDS bf16, B=avt direct)
__global__ __launch_bounds__(256) void k_out(
    const unsigned short* __restrict__ avt, const float* __restrict__ wo,
    const float* __restrict__ bo, const float* __restrict__ gamma,
    const float* __restrict__ x, float* __restrict__ out)
{
    const int nb = blockIdx.x;   // 16 tiles of 256 n
    const int cb = blockIdx.y;   // 8 tiles of 64 c
    const int b  = blockIdx.z;
    const int c0 = cb * 64;
    __shared__ unsigned short wl[64][72];   // [c][i], pad: stride 144B -> 2-way reads
    const int t = threadIdx.x;

    #pragma unroll
    for (int i4 = 0; i4 < 4; ++i4) {
        int row = i4 * 16 + (t >> 4);
        int col = (t & 15) * 4;
        float4 v = *(const float4*)(wo + (size_t)(c0 + row) * CPD + col);
        unsigned short tmp[4] = { f2bf(v.x), f2bf(v.y), f2bf(v.z), f2bf(v.w) };
        *(uint2*)&wl[row][col] = *(const uint2*)tmp;
    }
    __syncthreads();

    const int wv_ = t >> 6, L = t & 63, quad = L >> 4, l15 = L & 15;
    const int n0 = nb * 256 + wv_ * 64;
    const unsigned short* avb = avt + (size_t)b * NN * CPD;

    f4v acc[4][4];   // [ct][nt]
    #pragma unroll
    for (int a = 0; a < 4; ++a)
        #pragma unroll
        for (int d = 0; d < 4; ++d) acc[a][d] = (f4v){0.f, 0.f, 0.f, 0.f};

    #pragma unroll
    for (int ks = 0; ks < 2; ++ks) {
        const int ic = ks * 32 + quad * 8;
        s8v af[4], bf_[4];
        #pragma unroll
        for (int ct = 0; ct < 4; ++ct)
            af[ct] = *(const s8v*)(&wl[ct * 16 + l15][ic]);
        #pragma unroll
        for (int nt = 0; nt < 4; ++nt)
            bf_[nt] = *(const s8v*)(avb + (size_t)(n0 + nt * 16 + l15) * CPD + ic);
        #pragma unroll
        for (int ct = 0; ct < 4; ++ct)
            #pragma unroll
            for (int nt = 0; nt < 4; ++nt)
                acc[ct][nt] = __builtin_amdgcn_mfma_f32_16x16x32_bf16(
                    af[ct], bf_[nt], acc[ct][nt], 0, 0, 0);
    }

    const float g = gamma[0];
    #pragma unroll
    for (int ct = 0; ct < 4; ++ct)
        #pragma unroll
        for (int r = 0; r < 4; ++r) {
            int c = c0 + ct * 16 + quad * 4 + r;
            float bs = bo[c];
            #pragma unroll
            for (int nt = 0; nt < 4; ++nt) {
                int n = n0 + nt * 16 + l15;
                size_t idx = ((size_t)b * CIN + c) * NN + n;
                out[idx] = g * (acc[ct][nt][r] + bs) + x[idx];
            }
        }
}

extern "C" void kernel_launch(void* const* d_in, const int* in_sizes, int n_in,
                              void* d_out, int out_size, void* d_ws, size_t ws_size,
                              hipStream_t stream) {
    const float* x  = (const float*)d_in[0];
    const float* wq = (const float*)d_in[1];
    const float* bq = (const float*)d_in[2];
    const float* wk = (const float*)d_in[3];
    const float* bk = (const float*)d_in[4];
    const float* wv = (const float*)d_in[5];
    const float* bv = (const float*)d_in[6];
    const float* wo = (const float*)d_in[7];
    const float* bo = (const float*)d_in[8];
    const float* gm = (const float*)d_in[9];
    float* out = (float*)d_out;

    // workspace (bytes): peak 58.7 MB
    //   phase A: xt (33.5 MB, b-chunk of 8) | q 8.4 | k 8.4 | vt 8.4
    //   phase B (xt dead): epart 16.8 @0 | attn @16.8 MB | avt @25.2 MB
    char* wsb = (char*)d_ws;
    unsigned short* xt = (unsigned short*)wsb;
    unsigned short* q  = (unsigned short*)(wsb + 33554432);
    unsigned short* k  = (unsigned short*)(wsb + 41943040);
    unsigned short* vt = (unsigned short*)(wsb + 50331648);
    float*          epart = (float*)wsb;
    unsigned short* attn  = (unsigned short*)(wsb + 16777216);
    unsigned short* avt   = (unsigned short*)(wsb + 25165824);

    for (int chunk = 0; chunk < 2; ++chunk) {
        int b_base = chunk * 8;
        k_prep<<<dim3(64, 8, 8), 256, 0, stream>>>(x, xt, b_base);
        k_qkv<<<dim3(16, 3, 8), 256, 0, stream>>>(xt, wq, bq, wk, bk, wv, bv,
                                                  q, k, vt, b_base);
    }
    k_energy<<<dim3(64, 16), 64, 0, stream>>>(q, k, epart);
    k_softmax<<<dim3(64, 16), 64, 0, stream>>>(epart, attn);
    k_attnv<<<dim3(16, 16), 256, 0, stream>>>(vt, attn, avt);
    k_out<<<dim3(16, 8, 16), 256, 0, stream>>>(avt, wo, bo, gm, x, out);
}

// Round 3
// 339.709 us; speedup vs baseline: 1.4003x; 1.0860x over previous
//
#include <hip/hip_runtime.h>
#include <hip/hip_bf16.h>

// B=16, C=512, N=4096 (64x64), CP=64.
// out = gamma*(wo@softmax((wk x)(wq x)^T)@(wv x)+bo)+x
// 4-kernel bf16-MFMA pipeline, minimal global traffic:
//   k_qkv:    x read once (HBM floor), w in LDS, x gathered per-lane -> q,k [cp][n], vt [n][cp]
//   k_energy: 8 K-splits, LDS-atomic block reduction -> epart 2 MB fp32
//   k_softmax: rowwise softmax -> attn bf16
//   k_avout:  attn*V (avt in LDS only) + wo-proj + bias + gamma + residual, float4 epilogue

#define NN 4096
#define CIN 512
#define CPD 64

typedef short s8v __attribute__((ext_vector_type(8)));
typedef float f4v __attribute__((ext_vector_type(4)));

__device__ __forceinline__ unsigned short f2bf(float f) {
    union { float f; unsigned int u; } c; c.f = f;
    unsigned int r = c.u + 0x7FFFu + ((c.u >> 16) & 1u);   // RNE
    return (unsigned short)(r >> 16);
}

// ---------------- K1: QKV. A = w (LDS bf16, swizzled), B = x (direct global gather).
// grid (16 nb, 16 b), block 512 (8 waves, each 32 n-cols). D[row=o][col=n].
__global__ __launch_bounds__(512, 2) void k_qkv(
    const float* __restrict__ x,
    const float* __restrict__ wq, const float* __restrict__ bq,
    const float* __restrict__ wk, const float* __restrict__ bk,
    const float* __restrict__ wv, const float* __restrict__ bv,
    unsigned short* __restrict__ q, unsigned short* __restrict__ k,
    unsigned short* __restrict__ vt)
{
    const int nb = blockIdx.x, b = blockIdx.y;
    const int t = threadIdx.x;
    const int wv_ = t >> 6, L = t & 63, quad = L >> 4, l15 = L & 15;
    const int swz = (l15 & 7) * 8;

    __shared__ unsigned short wl[3][64 * 128];   // [p][o][c-chunk 128], 48 KB

    const float* wptr[3] = { wq, wk, wv };

    f4v acc[3][4][2];   // [p][ot][ntc]
    #pragma unroll
    for (int p = 0; p < 3; ++p)
        #pragma unroll
        for (int ot = 0; ot < 4; ++ot)
            #pragma unroll
            for (int nn = 0; nn < 2; ++nn) acc[p][ot][nn] = (f4v){0.f,0.f,0.f,0.f};

    const int n_col0 = nb * 256 + wv_ * 32 + l15;   // lane's column for ntc=0
    const size_t xbase = (size_t)b * CIN * NN;

    for (int cc = 0; cc < 4; ++cc) {            // c-chunks of 128
        __syncthreads();
        // stage w chunk (all 3 projections), fp32->bf16, XOR-swizzled
        {
            const int o   = t & 63;
            const int c16 = (t >> 6) * 16;
            const int osw = (o & 7) * 8;
            #pragma unroll
            for (int p = 0; p < 3; ++p) {
                const float* wp = wptr[p] + (size_t)o * CIN + cc * 128 + c16;
                unsigned short tmp[16];
                #pragma unroll
                for (int f = 0; f < 4; ++f) {
                    float4 v = *(const float4*)(wp + f * 4);
                    tmp[f*4+0] = f2bf(v.x); tmp[f*4+1] = f2bf(v.y);
                    tmp[f*4+2] = f2bf(v.z); tmp[f*4+3] = f2bf(v.w);
                }
                #pragma unroll
                for (int u = 0; u < 2; ++u)
                    *(uint4*)&wl[p][o * 128 + ((c16 + u * 8) ^ osw)] =
                        *(const uint4*)&tmp[u * 8];
            }
        }
        __syncthreads();

        #pragma unroll
        for (int ksl = 0; ksl < 4; ++ksl) {
            const int c = cc * 128 + ksl * 32 + quad * 8;
            // gather B-fragments from global x (lanes = consecutive n -> 64B segs)
            float bx0[8], bx1[8];
            #pragma unroll
            for (int j = 0; j < 8; ++j) {
                const float* xc = x + xbase + (size_t)(c + j) * NN + n_col0;
                bx0[j] = xc[0];
                bx1[j] = xc[16];
            }
            s8v bf0, bf1;
            #pragma unroll
            for (int j = 0; j < 8; ++j) {
                bf0[j] = (short)f2bf(bx0[j]);
                bf1[j] = (short)f2bf(bx1[j]);
            }
            const int cfrag = (ksl * 32 + quad * 8) ^ swz;
            #pragma unroll
            for (int p = 0; p < 3; ++p)
                #pragma unroll
                for (int ot = 0; ot < 4; ++ot) {
                    s8v af = *(const s8v*)&wl[p][(ot * 16 + l15) * 128 + cfrag];
                    acc[p][ot][0] = __builtin_amdgcn_mfma_f32_16x16x32_bf16(
                        af, bf0, acc[p][ot][0], 0, 0, 0);
                    acc[p][ot][1] = __builtin_amdgcn_mfma_f32_16x16x32_bf16(
                        af, bf1, acc[p][ot][1], 0, 0, 0);
                }
        }
    }

    // epilogue: D rows o = ot*16+quad*4+r, cols n = n_col0 + ntc*16
    const float* biasp[3] = { bq, bk, bv };
    #pragma unroll
    for (int p = 0; p < 2; ++p) {
        unsigned short* outp = ((p == 0) ? q : k) + (size_t)b * CPD * NN;
        #pragma unroll
        for (int ot = 0; ot < 4; ++ot) {
            float4 b4 = *(const float4*)(biasp[p] + ot * 16 + quad * 4);
            const float bsv[4] = { b4.x, b4.y, b4.z, b4.w };
            #pragma unroll
            for (int nn = 0; nn < 2; ++nn) {
                const int n = n_col0 + nn * 16;
                #pragma unroll
                for (int r = 0; r < 4; ++r) {
                    int o = ot * 16 + quad * 4 + r;
                    outp[(size_t)o * NN + n] = f2bf(acc[p][ot][nn][r] + bsv[r]);
                }
            }
        }
    }
    {
        unsigned short* vtb = vt + (size_t)b * NN * CPD;
        #pragma unroll
        for (int ot = 0; ot < 4; ++ot) {
            float4 b4 = *(const float4*)(bv + ot * 16 + quad * 4);
            const float bsv[4] = { b4.x, b4.y, b4.z, b4.w };
            #pragma unroll
            for (int nn = 0; nn < 2; ++nn) {
                const int n = n_col0 + nn * 16;
                unsigned short tmp[4];
                #pragma unroll
                for (int r = 0; r < 4; ++r) tmp[r] = f2bf(acc[2][ot][nn][r] + bsv[r]);
                *(uint2*)(vtb + (size_t)n * CPD + ot * 16 + quad * 4) = *(const uint2*)tmp;
            }
        }
    }
}

// ---------------- K2: energy partials, 8 K-splits, LDS-atomic block reduction.
__global__ __launch_bounds__(256) void k_energy(
    const unsigned short* __restrict__ q, const unsigned short* __restrict__ k,
    float* __restrict__ epart)   // [b][8][64][64] fp32
{
    const int s = blockIdx.x;   // 8 K-chunks of 512 n
    const int b = blockIdx.y;
    const int t = threadIdx.x;
    const int wv_ = t >> 6, L = t & 63, quad = L >> 4, l15 = L & 15;
    const unsigned short* kb = k + (size_t)b * CPD * NN;
    const unsigned short* qb = q + (size_t)b * CPD * NN;

    __shared__ float red[64 * 65];

    f4v acc[4][4];
    #pragma unroll
    for (int a = 0; a < 4; ++a)
        #pragma unroll
        for (int d = 0; d < 4; ++d) acc[a][d] = (f4v){0.f,0.f,0.f,0.f};

    const int nbase = s * 512 + wv_ * 128;
    #pragma unroll
    for (int ks = 0; ks < 4; ++ks) {
        const int n = nbase + ks * 32 + quad * 8;
        s8v af[4], bf_[4];
        #pragma unroll
        for (int it = 0; it < 4; ++it)
            af[it] = *(const s8v*)(kb + (size_t)(it * 16 + l15) * NN + n);
        #pragma unroll
        for (int jt = 0; jt < 4; ++jt)
            bf_[jt] = *(const s8v*)(qb + (size_t)(jt * 16 + l15) * NN + n);
        #pragma unroll
        for (int it = 0; it < 4; ++it)
            #pragma unroll
            for (int jt = 0; jt < 4; ++jt)
                acc[it][jt] = __builtin_amdgcn_mfma_f32_16x16x32_bf16(
                    af[it], bf_[jt], acc[it][jt], 0, 0, 0);
    }

    for (int idx = t; idx < 64 * 65; idx += 256) red[idx] = 0.f;
    __syncthreads();
    #pragma unroll
    for (int it = 0; it < 4; ++it)
        #pragma unroll
        for (int jt = 0; jt < 4; ++jt)
            #pragma unroll
            for (int r = 0; r < 4; ++r)
                atomicAdd(&red[(it * 16 + quad * 4 + r) * 65 + jt * 16 + l15],
                          acc[it][jt][r]);
    __syncthreads();
    float* ep = epart + ((size_t)b * 8 + s) * 4096;
    for (int idx = t; idx < 4096; idx += 256)
        ep[idx] = red[(idx >> 6) * 65 + (idx & 63)];
}

// ---------------- K3: sum 8 partials + softmax over j -> attn bf16 [b][i][j]
__global__ __launch_bounds__(64) void k_softmax(
    const float* __restrict__ epart, unsigned short* __restrict__ attn)
{
    const int i = blockIdx.x;
    const int b = blockIdx.y;
    const int j = threadIdx.x;
    float s = 0.f;
    #pragma unroll
    for (int sp = 0; sp < 8; ++sp)
        s += epart[((size_t)b * 8 + sp) * 4096 + i * 64 + j];
    float m = s;
    #pragma unroll
    for (int off = 32; off; off >>= 1) m = fmaxf(m, __shfl_xor(m, off));
    float e = __expf(s - m);
    float tot = e;
    #pragma unroll
    for (int off = 32; off; off >>= 1) tot += __shfl_xor(tot, off);
    attn[(size_t)b * 4096 + i * 64 + j] = f2bf(e / tot);
}

// ---------------- K4: fused attn*V + out-proj + residual.
// grid (32 nb, 16 b), block 256 (4 waves, each 32 n). n-tile 128.
// phase1: D1[i-row][n-col] = attn x vt -> avl LDS [n][i] (swizzled)
// phase2: D2[n-row][c-col] = avl x wo -> float4 epilogue along n
__global__ __launch_bounds__(256) void k_avout(
    const unsigned short* __restrict__ vt, const unsigned short* __restrict__ attn,
    const float* __restrict__ wo, const float* __restrict__ bo,
    const float* __restrict__ gamma, const float* __restrict__ x,
    float* __restrict__ out)
{
    const int nb = blockIdx.x, b = blockIdx.y;
    const int t = threadIdx.x;
    const int wv_ = t >> 6, L = t & 63, quad = L >> 4, l15 = L & 15;
    const int swz = (l15 & 7) * 8;

    __shared__ unsigned short wol[512 * 64];   // [c][i], swizzled, 64 KB
    __shared__ unsigned short avl[128 * 64];   // [n][i], swizzled, 16 KB

    // stage full wo (fp32 -> bf16)
    {
        const int i16 = (t & 3) * 16;
        #pragma unroll
        for (int pass = 0; pass < 8; ++pass) {
            const int c = (t >> 2) + pass * 64;
            const int csw = (c & 7) * 8;
            const float* wp = wo + (size_t)c * CPD + i16;
            unsigned short tmp[16];
            #pragma unroll
            for (int f = 0; f < 4; ++f) {
                float4 v = *(const float4*)(wp + f * 4);
                tmp[f*4+0] = f2bf(v.x); tmp[f*4+1] = f2bf(v.y);
                tmp[f*4+2] = f2bf(v.z); tmp[f*4+3] = f2bf(v.w);
            }
            #pragma unroll
            for (int u = 0; u < 2; ++u)
                *(uint4*)&wol[c * 64 + ((i16 + u * 8) ^ csw)] = *(const uint4*)&tmp[u*8];
        }
    }

    // phase 1: avt tile (128 n-cols), A = attn (global), B = vt (global)
    {
        const unsigned short* ab  = attn + (size_t)b * 4096;
        const unsigned short* vtb = vt + (size_t)b * NN * CPD;
        const int n0 = nb * 128;
        f4v acc1[4][2];   // [it][ntc]
        #pragma unroll
        for (int a = 0; a < 4; ++a)
            #pragma unroll
            for (int d = 0; d < 2; ++d) acc1[a][d] = (f4v){0.f,0.f,0.f,0.f};
        #pragma unroll
        for (int ks = 0; ks < 2; ++ks) {
            const int j = ks * 32 + quad * 8;
            s8v af[4], bf_[2];
            #pragma unroll
            for (int it = 0; it < 4; ++it)
                af[it] = *(const s8v*)(ab + (size_t)(it * 16 + l15) * 64 + j);
            #pragma unroll
            for (int nn = 0; nn < 2; ++nn)
                bf_[nn] = *(const s8v*)(vtb +
                    (size_t)(n0 + wv_ * 32 + nn * 16 + l15) * CPD + j);
            #pragma unroll
            for (int it = 0; it < 4; ++it)
                #pragma unroll
                for (int nn = 0; nn < 2; ++nn)
                    acc1[it][nn] = __builtin_amdgcn_mfma_f32_16x16x32_bf16(
                        af[it], bf_[nn], acc1[it][nn], 0, 0, 0);
        }
        // write avl[n][i]: i = it*16+quad*4+r, n_local = wv_*32+ntc*16+l15
        #pragma unroll
        for (int it = 0; it < 4; ++it)
            #pragma unroll
            for (int nn = 0; nn < 2; ++nn) {
                const int nloc = wv_ * 32 + nn * 16 + l15;
                unsigned short tmp[4];
                #pragma unroll
                for (int r = 0; r < 4; ++r) tmp[r] = f2bf(acc1[it][nn][r]);
                *(uint2*)&avl[nloc * 64 + ((it * 16 + quad * 4) ^ swz)] =
                    *(const uint2*)tmp;
            }
    }
    __syncthreads();

    // phase 2: out = gamma*(wo@av + bo) + x, float4 along n
    const float g = gamma[0];
    const int n0 = nb * 128;
    for (int cb = 0; cb < 8; ++cb) {
        f4v acc2[2][4];   // [nt][ct]
        #pragma unroll
        for (int a = 0; a < 2; ++a)
            #pragma unroll
            for (int d = 0; d < 4; ++d) acc2[a][d] = (f4v){0.f,0.f,0.f,0.f};
        #pragma unroll
        for (int ks = 0; ks < 2; ++ks) {
            const int ic = (ks * 32 + quad * 8) ^ swz;
            s8v af2[2], bf2[4];
            #pragma unroll
            for (int nt = 0; nt < 2; ++nt)
                af2[nt] = *(const s8v*)&avl[(wv_ * 32 + nt * 16 + l15) * 64 + ic];
            #pragma unroll
            for (int ct = 0; ct < 4; ++ct)
                bf2[ct] = *(const s8v*)&wol[(cb * 64 + ct * 16 + l15) * 64 + ic];
            #pragma unroll
            for (int nt = 0; nt < 2; ++nt)
                #pragma unroll
                for (int ct = 0; ct < 4; ++ct)
                    acc2[nt][ct] = __builtin_amdgcn_mfma_f32_16x16x32_bf16(
                        af2[nt], bf2[ct], acc2[nt][ct], 0, 0, 0);
        }
        // D2 rows n = n0+wv_*32+nt*16+quad*4+r, cols c = cb*64+ct*16+l15
        #pragma unroll
        for (int nt = 0; nt < 2; ++nt)
            #pragma unroll
            for (int ct = 0; ct < 4; ++ct) {
                const int c = cb * 64 + ct * 16 + l15;
                const float bs = bo[c];
                const int nbase = n0 + wv_ * 32 + nt * 16 + quad * 4;
                const size_t idx = ((size_t)b * CIN + c) * NN + nbase;
                float4 xr = *(const float4*)(x + idx);
                float4 r4;
                r4.x = g * (acc2[nt][ct][0] + bs) + xr.x;
                r4.y = g * (acc2[nt][ct][1] + bs) + xr.y;
                r4.z = g * (acc2[nt][ct][2] + bs) + xr.z;
                r4.w = g * (acc2[nt][ct][3] + bs) + xr.w;
                *(float4*)(out + idx) = r4;
            }
    }
}

extern "C" void kernel_launch(void* const* d_in, const int* in_sizes, int n_in,
                              void* d_out, int out_size, void* d_ws, size_t ws_size,
                              hipStream_t stream) {
    const float* x  = (const float*)d_in[0];
    const float* wq = (const float*)d_in[1];
    const float* bq = (const float*)d_in[2];
    const float* wk = (const float*)d_in[3];
    const float* bk = (const float*)d_in[4];
    const float* wv = (const float*)d_in[5];
    const float* bv = (const float*)d_in[6];
    const float* wo = (const float*)d_in[7];
    const float* bo = (const float*)d_in[8];
    const float* gm = (const float*)d_in[9];
    float* out = (float*)d_out;

    // workspace (bytes), total ~27.4 MB:
    char* wsb = (char*)d_ws;
    unsigned short* q     = (unsigned short*)wsb;                 //  8.39 MB
    unsigned short* k     = (unsigned short*)(wsb + 8388608);     //  8.39 MB
    unsigned short* vt    = (unsigned short*)(wsb + 16777216);    //  8.39 MB
    float*          epart = (float*)(wsb + 25165824);             //  2.10 MB
    unsigned short* attn  = (unsigned short*)(wsb + 27262976);    //  0.13 MB

    k_qkv<<<dim3(16, 16), 512, 0, stream>>>(x, wq, bq, wk, bk, wv, bv, q, k, vt);
    k_energy<<<dim3(8, 16), 256, 0, stream>>>(q, k, epart);
    k_softmax<<<dim3(64, 16), 64, 0, stream>>>(epart, attn);
    k_avout<<<dim3(32, 16), 256, 0, stream>>>(vt, attn, wo, bo, gm, x, out);
}